// Round 4
// baseline (127.087 us; speedup 1.0000x reference)
//
#include <hip/hip_runtime.h>

#define B_    512
#define IN_   256
#define H_    512
#define OUT_  64
#define NDEATH (B_ - 1)
#define NSORT  512          // NDEATH padded to pow2 for bitonic sort / bsearch
#define RTOL_ 1e-6
#define ATOL_ 1e-8
#define NBLK  512           // R17: 2 blocks/CU -> barrier-independent pipelines
#define NTHR  256           // 4 waves/block
#define NGRP  32            // 32 groups of 16 blocks (16-row strips)
#define KT    32            // K-tile (per K-half), split-K x2

typedef __attribute__((ext_vector_type(4))) double d4_t;

// agent-visible store: relaxed atomic, bypasses L2 -> lands at L3 coherence
// point. No dirty L2 lines => barriers need NO wbl2/inv fences. (R11-verified)
__device__ __forceinline__ void ast(double* p, double v) {
    __hip_atomic_store(p, v, __ATOMIC_RELAXED, __HIP_MEMORY_SCOPE_AGENT);
}
__device__ __forceinline__ double ald(const double* p) {
    return __hip_atomic_load(p, __ATOMIC_RELAXED, __HIP_MEMORY_SCOPE_AGENT);
}
__device__ __forceinline__ unsigned aldu(const unsigned* p) {
    return __hip_atomic_load(p, __ATOMIC_RELAXED, __HIP_MEMORY_SCOPE_AGENT);
}
__device__ __forceinline__ void aadd(unsigned* p) {
    __hip_atomic_fetch_add(p, 1u, __ATOMIC_RELAXED, __HIP_MEMORY_SCOPE_AGENT);
}

// ---------------------------------------------------------------------------
// LDS-only barrier (R15): lgkmcnt(0)+s_barrier. Global prefetches ride across;
// the K-loop's only cross-wave dependency is LDS staging.
// ---------------------------------------------------------------------------
__device__ __forceinline__ void lbar() {
    asm volatile("s_waitcnt lgkmcnt(0)" ::: "memory");
    __builtin_amdgcn_s_barrier();
    asm volatile("" ::: "memory");
}

// ---------------------------------------------------------------------------
// 16-way group barrier (R11-verified protocol). Full __syncthreads REQUIRED:
// the vmcnt(0) drain makes prior ast stores visible before the arrival.
// ---------------------------------------------------------------------------
__device__ __forceinline__ void gbar(unsigned* cnt, unsigned nb) {
    __syncthreads();
    if (threadIdx.x == 0) {
        aadd(cnt);
        while (aldu(cnt) < nb) __builtin_amdgcn_s_sleep(1);
    }
    __syncthreads();
}

// ---------------------------------------------------------------------------
// two-level device barrier (R16): 16-way group arrivals in parallel + NGRP-way
// root promoted by group leaders. All blocks release on root==NGRP.
// ---------------------------------------------------------------------------
__device__ __forceinline__ void gbar2(unsigned* gslot, unsigned* root,
                                      int leader) {
    __syncthreads();
    if (threadIdx.x == 0) {
        aadd(gslot);
        if (leader) {
            while (aldu(gslot) < 16u) __builtin_amdgcn_s_sleep(1);
            aadd(root);
        }
        while (aldu(root) < (unsigned)NGRP) __builtin_amdgcn_s_sleep(1);
    }
    __syncthreads();
}

// ---------------------------------------------------------------------------
// per-block: bitonic-sort deaths into LDS, emit sorted tolerance windows.
// 256 threads, 512 elements.
// ---------------------------------------------------------------------------
__device__ void sort_windows(const float* __restrict__ deaths,
                             double* sd, double* slo, double* shi, int t) {
    int i1 = t + 256;
    sd[t]  = (t  < NDEATH) ? (double)deaths[t]  : 1e300;
    sd[i1] = (i1 < NDEATH) ? (double)deaths[i1] : 1e300;
    __syncthreads();
    for (int k = 2; k <= NSORT; k <<= 1) {
        for (int j = k >> 1; j > 0; j >>= 1) {
            int l = ((t & ~(j - 1)) << 1) | (t & (j - 1));   // pair (l, l+j)
            int p = l + j;
            bool up = ((l & k) == 0);
            double a = sd[l], b = sd[p];
            if ((a > b) == up) { sd[l] = b; sd[p] = a; }
            __syncthreads();
        }
    }
    for (int i = t; i < NSORT; i += 256) {
        double d = sd[i];
        double w = ATOL_ + RTOL_ * fabs(d);
        slo[i] = d - w;
        shi[i] = d + w;
    }
    __syncthreads();
}

// ---------------------------------------------------------------------------
// f64 MFMA GEMM phase, R17: 16x32 tile, 4 waves = 2 col-halves x 2 K-halves.
// A staged via LDS (depth-3 register prefetch); B direct global->reg
// (coalesced, per-wave private); two accumulators split the MFMA chain.
// One lgkm-only barrier per K-tile. Summation order identical to R16.
// ---------------------------------------------------------------------------
template <typename TIN, bool RELU>
__device__ void gemm_dev(const TIN* __restrict__ A, const float* __restrict__ W,
                         const float* __restrict__ bias, double* __restrict__ C,
                         int N, int K, int tile, int t,
                         double (&As)[2][2][KT][17]) {
    const int lane  = t & 63;
    const int colq  = (t >> 6) & 1;     // 16-col half
    const int kw    = t >> 7;           // K-half (consume == stage: t>>7)
    const int nbx   = N >> 5;
    const int row0  = (tile / nbx) << 4;
    const int col0  = (tile % nbx) << 5;

    const int tg    = t & 127;          // 128-thread staging map per K-half
    const int akk   = tg & 31;          // k within A tile
    const int amm   = tg >> 5;          // base row (rows amm+4p, p=0..3)
    const int kbase = kw * (K >> 1);
    const int nkt   = K >> 6;           // K-tiles per half

    const int mrow  = lane & 15;
    const int kq    = lane >> 4;
    const int ncol  = colq * 16 + (lane & 15);

    TIN   ar[3][4];
    float br[3][8];

    auto load_a = [&](int rs, int kt) {
        const int k0 = kbase + (kt << 5);
        #pragma unroll
        for (int p = 0; p < 4; ++p)
            ar[rs][p] = A[(size_t)(row0 + amm + 4 * p) * K + k0 + akk];
    };
    auto load_b = [&](int rs, int kt) {
        const int k0 = kbase + (kt << 5);
        const float* wp = W + (size_t)(k0 + kq) * N + col0 + ncol;
        #pragma unroll
        for (int ks = 0; ks < 8; ++ks)
            br[rs][ks] = wp[(size_t)(4 * ks) * N];
    };
    auto stage_a = [&](int rs, int buf) {
        #pragma unroll
        for (int p = 0; p < 4; ++p)
            As[kw][buf][akk][amm + 4 * p] = (double)ar[rs][p];
    };

    load_a(0, 0); load_b(0, 0);
    if (nkt > 1) { load_a(1, 1); load_b(1, 1); }
    if (nkt > 2) { load_a(2, 2); load_b(2, 2); }
    stage_a(0, 0);
    lbar();

    d4_t c4a = {0.0, 0.0, 0.0, 0.0};
    d4_t c4b = {0.0, 0.0, 0.0, 0.0};

    for (int kt = 0; kt < nkt; ++kt) {
        const int cur = kt & 1;
        const int rs  = kt % 3;
        #pragma unroll
        for (int ks = 0; ks < 4; ++ks) {
            double av = As[kw][cur][ks * 4 + kq][mrow];
            c4a = __builtin_amdgcn_mfma_f64_16x16x4f64(av, (double)br[rs][ks],
                                                       c4a, 0, 0, 0);
        }
        #pragma unroll
        for (int ks = 4; ks < 8; ++ks) {
            double av = As[kw][cur][ks * 4 + kq][mrow];
            c4b = __builtin_amdgcn_mfma_f64_16x16x4f64(av, (double)br[rs][ks],
                                                       c4b, 0, 0, 0);
        }
        // slot rs fully consumed -> refill for kt+3
        if (kt + 3 < nkt) { load_a(rs, kt + 3); load_b(rs, kt + 3); }
        if (kt + 1 < nkt) stage_a((kt + 1) % 3, cur ^ 1); // disjoint buffer
        lbar();                                           // lgkm-only
    }

    d4_t c4 = c4a + c4b;

    // combine K-half partials: kw1 publishes, kw0 adds + epilogue.
    // cEx aliases As (all K-loop reads fenced by the final loop barrier).
    double (*cEx)[16][17] = (double (*)[16][17])(&As[0][0][0][0]);
    const int r4 = (lane >> 4) * 4;
    if (kw == 1) {
        #pragma unroll
        for (int r = 0; r < 4; ++r)
            cEx[colq][r4 + r][lane & 15] = c4[r];
    }
    lbar();
    if (kw == 0) {
        #pragma unroll
        for (int r = 0; r < 4; ++r) {
            int row = row0 + r4 + r;
            int col = col0 + colq * 16 + (lane & 15);
            double v = c4[r] + cEx[colq][r4 + r][lane & 15] + (double)bias[col];
            if (RELU) v = v > 0.0 ? v : 0.0;
            ast(&C[(size_t)row * N + col], v);
        }
    }
}

// ---------------------------------------------------------------------------
// column c: mean + target-MSE partial + compactness partial -> global slots
// 256 threads, two rows per thread.
// ---------------------------------------------------------------------------
__device__ void mc_dev(const float* __restrict__ target,
                       const double* __restrict__ y,
                       double* __restrict__ t_part, double* __restrict__ c_part,
                       int c, int t) {
    const int wave = t >> 6, lane = t & 63;
    double v0 = y[(size_t)t * OUT_ + c];
    double v1 = y[(size_t)(t + 256) * OUT_ + c];
    double s = v0 + v1;
    for (int off = 32; off; off >>= 1) s += __shfl_down(s, off);
    __shared__ double swm[4];
    __shared__ double smean;
    if (lane == 0) swm[wave] = s;
    __syncthreads();
    if (t == 0) smean = (swm[0] + swm[1] + swm[2] + swm[3]) / (double)B_;
    __syncthreads();
    double m = smean;
    double d0 = (double)target[(size_t)t * OUT_ + c] - v0;
    double d1 = (double)target[(size_t)(t + 256) * OUT_ + c] - v1;
    double t_s = d0 * d0 + d1 * d1;
    double c_s = fabs(v0 - m) + fabs(v1 - m);
    for (int off = 32; off; off >>= 1) {
        t_s += __shfl_down(t_s, off);
        c_s += __shfl_down(c_s, off);
    }
    __shared__ double st[4], sc[4];
    if (lane == 0) { st[wave] = t_s; sc[wave] = c_s; }
    __syncthreads();
    if (t == 0) {
        ast(&t_part[c], st[0] + st[1] + st[2] + st[3]);
        ast(&c_part[c], sc[0] + sc[1] + sc[2] + sc[3]);
    }
}

// ---------------------------------------------------------------------------
// pdist + sorted-window match. R17: 512 blocks; block b handles rows
// (s, 510-s) with s=b>>1, taking only pairs of parity b&1 (j stride 2).
// ---------------------------------------------------------------------------
__device__ __forceinline__ double pair_val(const double* __restrict__ yrow_s,
                                           const double* __restrict__ yj,
                                           const double* __restrict__ slo,
                                           const double* __restrict__ shi) {
    double s = 0.0;
    #pragma unroll
    for (int d = 0; d < OUT_; d += 2) {
        double2 v = *(const double2*)(yj + d);
        double d0 = yrow_s[d]     - v.x;
        double d1 = yrow_s[d + 1] - v.y;
        s = fma(d0, d0, s);
        s = fma(d1, d1, s);
    }
    double pd = sqrt(s);
    int pos = 0;
    #pragma unroll
    for (int step = NSORT / 2; step; step >>= 1) {
        if (slo[pos + step - 1] <= pd) pos += step;
    }
    bool m = (pos > 0) && (shi[pos - 1] >= pd);
    return m ? pd : 0.0;
}

__device__ void pdist_dev(const double* __restrict__ y,
                          double* __restrict__ hom_part, int bid, int t,
                          double* yA, double* yB,
                          const double* slo, const double* shi) {
    const int iA  = bid >> 1;
    const int iB  = 510 - iA;     // == iA when iA == 255
    const int par = bid & 1;
    if (t < OUT_)            yA[t]        = y[(size_t)iA * OUT_ + t];
    else if (t < 2 * OUT_)   yB[t - OUT_] = y[(size_t)iB * OUT_ + (t - OUT_)];
    __syncthreads();

    double local = 0.0;
    for (int j = iA + 1 + par + 2 * t; j < B_; j += 2 * NTHR)
        local += pair_val(yA, y + (size_t)j * OUT_, slo, shi);
    if (iB != iA)
        for (int j = iB + 1 + par + 2 * t; j < B_; j += 2 * NTHR)
            local += pair_val(yB, y + (size_t)j * OUT_, slo, shi);

    for (int off = 32; off; off >>= 1) local += __shfl_down(local, off);
    __shared__ double sw[4];
    int wave = t >> 6, lane = t & 63;
    if (lane == 0) sw[wave] = local;
    __syncthreads();
    if (t == 0) ast(&hom_part[bid], sw[0] + sw[1] + sw[2] + sw[3]);
}

// ---------------------------------------------------------------------------
// single fused persistent kernel, R17: 512 blocks x 256 threads (2 blocks/CU,
// barrier-independent pipelines). 32 groups of 16 blocks; group g owns 16-row
// strip g; P0..P2 group-local 16-arrival barriers; two-level device barrier
// before pdist; two-level finalize with block 0 as fixed finalizer.
// Counters (uints): grp g slot p -> cnt[g*32+p] (p=0..4); pdist root cnt[1024];
// finalize root cnt[1025]. Window broadcast: wbc[0..511]=lo, wbc[512..1023]=hi.
// ---------------------------------------------------------------------------
__global__ __launch_bounds__(NTHR) void fused_k(
    const float* __restrict__ batch, const float* __restrict__ target,
    const float* __restrict__ W1, const float* __restrict__ b1,
    const float* __restrict__ W2, const float* __restrict__ b2,
    const float* __restrict__ W3, const float* __restrict__ b3,
    const float* __restrict__ Wout, const float* __restrict__ bout,
    const float* __restrict__ deaths, float* __restrict__ out,
    double* __restrict__ hA, double* __restrict__ hB,
    double* __restrict__ hC, double* __restrict__ yv,
    double* __restrict__ hom_part, double* __restrict__ t_part,
    double* __restrict__ c_part, unsigned* __restrict__ cnt,
    double* __restrict__ wbc) {
    const int bid = blockIdx.x;
    const int t   = threadIdx.x;
    const int g   = bid >> 4;     // group = 16-row strip
    const int c   = bid & 15;     // col-tile within group
    unsigned* gc  = cnt + g * 32; // group-private counter line

    __shared__ double As[2][2][KT][17];
    __shared__ double slo[NSORT], shi[NSORT];
    __shared__ double yA[OUT_], yB[OUT_];
    double* sd = &As[0][0][0][0];             // sort scratch alias (512 dbl)

    // P0..P2: three GEMMs; tile = bid (row0=16g, col0=32c).
    gemm_dev<float,  true>(batch, W1, b1, hA, H_, IN_, bid, t, As);
    gbar(&gc[0], 16);
    gemm_dev<double, true>(hA, W2, b2, hB, H_, H_, bid, t, As);
    gbar(&gc[1], 16);
    gemm_dev<double, true>(hB, W3, b3, hC, H_, H_, bid, t, As);
    gbar(&gc[2], 16);

    // P3: Wout tile g*2+c on c<2 (16-row strip g -> group-local dep); c>=2
    // sort. bid==2 publishes the sorted windows for the c<2 blocks.
    if (c < 2) {
        gemm_dev<double, false>(hC, Wout, bout, yv, OUT_, H_, g * 2 + c, t, As);
    } else {
        sort_windows(deaths, sd, slo, shi, t);
        if (bid == 2) {
            for (int i = t; i < NSORT; i += 256) {
                ast(&wbc[i],         slo[i]);
                ast(&wbc[NSORT + i], shi[i]);
            }
        }
    }

    // two-level device barrier: pdist needs all of yv + window broadcast
    gbar2(&gc[3], &cnt[1024], c == 0);
    if (c < 2) {
        for (int i = t; i < NSORT; i += 256) {
            slo[i] = ald(&wbc[i]);
            shi[i] = ald(&wbc[NSORT + i]);
        }
        __syncthreads();
    }

    // P4: pdist on all 512 blocks; mean/MSE/compactness on blocks 0..63
    pdist_dev(yv, hom_part, bid, t, yA, yB, slo, shi);
    if (bid < OUT_) mc_dev(target, yv, t_part, c_part, bid, t);

    // P5: two-level finalize arrivals; block 0 is the fixed finalizer.
    __syncthreads();   // vmcnt(0) drain: part stores visible before arrival
    if (t == 0) {
        aadd(&gc[4]);
        if (c == 0) {
            while (aldu(&gc[4]) < 16u) __builtin_amdgcn_s_sleep(1);
            aadd(&cnt[1025]);
        }
    }
    if (bid != 0) return;
    if (t == 0)
        while (aldu(&cnt[1025]) < (unsigned)NGRP) __builtin_amdgcn_s_sleep(1);
    __syncthreads();

    {
        double h = ald(&hom_part[t]) + ald(&hom_part[t + 256]);
        double tp = 0.0, cp = 0.0;
        if (t < OUT_) { tp = ald(&t_part[t]); cp = ald(&c_part[t]); }
        for (int off = 32; off; off >>= 1) {
            h  += __shfl_down(h,  off);
            tp += __shfl_down(tp, off);
            cp += __shfl_down(cp, off);
        }
        __shared__ double sh[4], stp[4], scp[4];
        int wave = t >> 6, lane = t & 63;
        if (lane == 0) { sh[wave] = h; stp[wave] = tp; scp[wave] = cp; }
        __syncthreads();
        if (t == 0) {
            double hs = sh[0]  + sh[1]  + sh[2]  + sh[3];
            double ts = stp[0] + stp[1] + stp[2] + stp[3];
            double cs = scp[0] + scp[1] + scp[2] + scp[3];
            out[0] = (float)(ts / (double)(B_ * OUT_) + hs + 0.01 * cs);
        }
    }
}

extern "C" void kernel_launch(void* const* d_in, const int* in_sizes, int n_in,
                              void* d_out, int out_size, void* d_ws, size_t ws_size,
                              hipStream_t stream) {
    const float* batch  = (const float*)d_in[0];
    const float* target = (const float*)d_in[1];
    const float* W1     = (const float*)d_in[2];
    const float* b1     = (const float*)d_in[3];
    const float* W2     = (const float*)d_in[4];
    const float* b2     = (const float*)d_in[5];
    const float* W3     = (const float*)d_in[6];
    const float* b3     = (const float*)d_in[7];
    const float* Wout   = (const float*)d_in[8];
    const float* bout   = (const float*)d_in[9];
    const float* deaths = (const float*)d_in[10];
    float* out = (float*)d_out;

    double* hA       = (double*)d_ws;              // 512*512
    double* hB       = hA + (size_t)B_ * H_;       // 512*512
    double* hC       = hB + (size_t)B_ * H_;       // 512*512
    double* yv       = hC + (size_t)B_ * H_;       // 512*64
    double* hom_part = yv + (size_t)B_ * OUT_;     // 512
    double* t_part   = hom_part + NBLK;            // 64
    double* c_part   = t_part + OUT_;              // 64
    unsigned* cnt    = (unsigned*)(c_part + OUT_); // 1088 uints
    double* wbc      = (double*)(cnt + 1088);      // 1024 doubles (lo|hi)

    hipMemsetAsync(cnt, 0, 1088 * sizeof(unsigned), stream);

    fused_k<<<dim3(NBLK), dim3(NTHR), 0, stream>>>(
        batch, target, W1, b1, W2, b2, W3, b3, Wout, bout, deaths, out,
        hA, hB, hC, yv, hom_part, t_part, c_part, cnt, wbc);
}